// Round 14
// baseline (496.770 us; speedup 1.0000x reference)
//
#include <hip/hip_runtime.h>
#include <hip/hip_bf16.h>
#include <stdint.h>
#include <stddef.h>

#define NN 2048
#define NB 16

typedef unsigned int u32;
typedef unsigned short u16;

// ---------------------------------------------------------------- KNN -------
// 8-partition scan: 32 queries/block (256 thr), 8 threads/query, 256 pts
// each. Conservative f32 screen (running thr from the exact f64 list) +
// exact f64 distance + stable sorted top-16 insert (strict <, lower index
// first) — logic identical to R11 (110us version), just 8 partitions.
// Per-thread sorted lists written to global scratch; exact 8-way merge in a
// separate kernel (ties -> lower partition = lower index block) => final
// (d, m)-lexicographic order bit-identical to the monolithic f64 scan.
// Occupancy: 32768*8 threads = 4096 waves -> 16 waves/CU (2x the 4-part
// version's thread-count cap); LDS = sp only (33.4KB) -> 4 blocks/CU.
__global__ __launch_bounds__(256) void knn_kernel(const float* __restrict__ pc,
                                                  double* __restrict__ dbuf,
                                                  u16* __restrict__ ibuf) {
  __shared__ float4 sp[8 * 261];  // 261 pad: partition bases on distinct banks
  const int t = threadIdx.x;
  const int b = blockIdx.x >> 6;
  const int qbase = (blockIdx.x & 63) << 5;
  const float* __restrict__ P = pc + (size_t)b * (3 * NN);
  for (int i = t; i < NN; i += 256) {
    sp[(i >> 8) * 261 + (i & 255)] =
        make_float4(P[i], P[NN + i], P[2 * NN + i], 0.f);
  }
  __syncthreads();
  const int qloc = t >> 3;
  const int part = t & 7;
  const int n = qbase + qloc;
  const float4 q = sp[(n >> 8) * 261 + (n & 255)];
  const double qx = (double)q.x, qy = (double)q.y, qz = (double)q.z;
  double bd[16];
  int bi[16];
#pragma unroll
  for (int j = 0; j < 16; ++j) { bd[j] = __builtin_inf(); bi[j] = 0; }
  float thr = __builtin_inff();
  const float4* __restrict__ base = &sp[part * 261];
  const int m0 = part << 8;
  for (int j0 = 0; j0 < 256; j0 += 32) {
    u32 mask = 0;
#pragma unroll
    for (int jj = 0; jj < 32; ++jj) {
      const float4 s = base[j0 + jj];
      const float dx = q.x - s.x;
      const float dy = q.y - s.y;
      const float dz = q.z - s.z;
      const float d = fmaf(dx, dx, fmaf(dy, dy, dz * dz));
      mask |= (d <= thr) ? (1u << jj) : 0u;
    }
    while (mask) {
      const int jj = __ffs(mask) - 1;
      mask &= mask - 1;
      const float4 s = base[j0 + jj];
      const double dx = qx - (double)s.x;
      const double dy = qy - (double)s.y;
      const double dz = qz - (double)s.z;
      const double d = dx * dx + dy * dy + dz * dz;
      if (d < bd[15]) {
        const int m = m0 + j0 + jj;
        bool cont = true;
#pragma unroll
        for (int j = 15; j >= 1; --j) {
          const bool mv = d < bd[j - 1];
          if (cont) {
            bd[j] = mv ? bd[j - 1] : d;
            bi[j] = mv ? bi[j - 1] : m;
          }
          cont = cont && mv;
        }
        if (cont) { bd[0] = d; bi[0] = m; }
        thr = (float)bd[15] * 1.00002f;
      }
    }
  }
  const size_t qb = ((size_t)((b << 11) + n)) * 128 + (size_t)part * 16;
#pragma unroll
  for (int j = 0; j < 16; ++j) {
    dbuf[qb + j] = bd[j];
    ibuf[qb + j] = (u16)bi[j];
  }
}

// --------------------------------------------- KNN exact 8-way merge --------
// One thread per query: merge 8 sorted 16-lists by exact f64 key; ties ->
// lowest partition (= lowest index block); within-list order is stable.
__global__ __launch_bounds__(256) void knn_merge(const double* __restrict__ dbuf,
                                                 const u16* __restrict__ ibuf,
                                                 int* __restrict__ idx16) {
  const int q = blockIdx.x * 256 + threadIdx.x;
  const size_t base = (size_t)q * 128;
  const double INF = __builtin_inf();
  double c0 = dbuf[base], c1 = dbuf[base + 16], c2 = dbuf[base + 32],
         c3 = dbuf[base + 48], c4 = dbuf[base + 64], c5 = dbuf[base + 80],
         c6 = dbuf[base + 96], c7 = dbuf[base + 112];
  int h0 = 0, h1 = 0, h2 = 0, h3 = 0, h4 = 0, h5 = 0, h6 = 0, h7 = 0;
  int out[16];
#pragma unroll
  for (int j = 0; j < 16; ++j) {
    double mv = c0;
    int mp = 0;
    if (c1 < mv) { mv = c1; mp = 1; }
    if (c2 < mv) { mv = c2; mp = 2; }
    if (c3 < mv) { mv = c3; mp = 3; }
    if (c4 < mv) { mv = c4; mp = 4; }
    if (c5 < mv) { mv = c5; mp = 5; }
    if (c6 < mv) { mv = c6; mp = 6; }
    if (c7 < mv) { mv = c7; mp = 7; }
    if (mp == 0) { out[j] = ibuf[base + h0]; ++h0; c0 = (h0 < 16) ? dbuf[base + h0] : INF; }
    else if (mp == 1) { out[j] = ibuf[base + 16 + h1]; ++h1; c1 = (h1 < 16) ? dbuf[base + 16 + h1] : INF; }
    else if (mp == 2) { out[j] = ibuf[base + 32 + h2]; ++h2; c2 = (h2 < 16) ? dbuf[base + 32 + h2] : INF; }
    else if (mp == 3) { out[j] = ibuf[base + 48 + h3]; ++h3; c3 = (h3 < 16) ? dbuf[base + 48 + h3] : INF; }
    else if (mp == 4) { out[j] = ibuf[base + 64 + h4]; ++h4; c4 = (h4 < 16) ? dbuf[base + 64 + h4] : INF; }
    else if (mp == 5) { out[j] = ibuf[base + 80 + h5]; ++h5; c5 = (h5 < 16) ? dbuf[base + 80 + h5] : INF; }
    else if (mp == 6) { out[j] = ibuf[base + 96 + h6]; ++h6; c6 = (h6 < 16) ? dbuf[base + 96 + h6] : INF; }
    else { out[j] = ibuf[base + 112 + h7]; ++h7; c7 = (h7 < 16) ? dbuf[base + 112 + h7] : INF; }
  }
  int4* op = (int4*)(idx16 + ((size_t)q << 4));
  op[0] = make_int4(out[0], out[1], out[2], out[3]);
  op[1] = make_int4(out[4], out[5], out[6], out[7]);
  op[2] = make_int4(out[8], out[9], out[10], out[11]);
  op[3] = make_int4(out[12], out[13], out[14], out[15]);
}

// ------------------- pack G = [h|f1|cost] + pack gate weights ---------------
__global__ __launch_bounds__(256) void pack_all(
    const float* __restrict__ h, const float* __restrict__ f1,
    const float* __restrict__ cost, const float* __restrict__ gzw,
    const float* __restrict__ grw, const float* __restrict__ gqw,
    float* __restrict__ G, float* __restrict__ Wzr, float* __restrict__ Wq) {
  __shared__ float tile[64][133];
  const int t = threadIdx.x;
  if (blockIdx.x >= 256) {
    const int i = (blockIdx.x - 256) * 256 + t;
    if (i < 220 * 128) {
      const int row = i >> 7, col = i & 127;
      float v = 0.f;
      if (row < 214)
        v = (col < 64) ? gzw[row * 64 + col] : grw[row * 64 + (col - 64)];
      Wzr[i] = v;
    } else if (i < 220 * 128 + 220 * 64) {
      const int iq = i - 220 * 128;
      const int row = iq >> 6;
      Wq[iq] = (row < 214) ? gqw[iq] : 0.f;
    }
    return;
  }
  const int b = blockIdx.x >> 4;
  const int n0 = (blockIdx.x & 15) << 7;
  const float* srcs[3] = {h, f1, cost};
#pragma unroll
  for (int a = 0; a < 3; ++a) {
    const float* __restrict__ S = srcs[a] + (size_t)b * 64 * NN;
    __syncthreads();
#pragma unroll
    for (int rep = 0; rep < 32; ++rep) {
      const int idx = rep * 256 + t;
      const int c = idx >> 7, n = idx & 127;
      tile[c][n] = S[c * NN + n0 + n];
    }
    __syncthreads();
#pragma unroll
    for (int rep = 0; rep < 32; ++rep) {
      const int idx = rep * 256 + t;
      const int n = idx >> 6, c = idx & 63;
      G[((size_t)((b << 11) + n0 + n)) * 192 + a * 64 + c] = tile[c][n];
    }
  }
}

// ------------------------------------------------------ SA1 chain -----------
template <int NL>
__global__ __launch_bounds__(256) void sa1_chain(
    const float* __restrict__ pc, const float* __restrict__ flow,
    const int* __restrict__ idx16,
    const float* __restrict__ W0, const float* __restrict__ b0,
    const float* __restrict__ W1, const float* __restrict__ b1,
    const float* __restrict__ W2, const float* __restrict__ b2,
    const float* __restrict__ st0, const float* __restrict__ st1,
    float* __restrict__ ff1max, float* __restrict__ statsOut) {
  __shared__ float sX[256][36];
  __shared__ float ssum[32], ssq[32];
  const int t = threadIdx.x;
  const int i0 = blockIdx.x << 8;
  const int b = i0 >> 15;
  const float invM = 1.f / 32768.f;
  if (t < 32) { ssum[t] = 0.f; ssq[t] = 0.f; }
  {
    const int i = i0 + t;
    const int n = (i & 32767) >> 4;
    const int mi = idx16[i];
    const float* P = pc + (size_t)b * (3 * NN);
    const float* F = flow + (size_t)b * (3 * NN);
    sX[t][0] = P[mi] - P[n];
    sX[t][1] = P[NN + mi] - P[NN + n];
    sX[t][2] = P[2 * NN + mi] - P[2 * NN + n];
    sX[t][3] = F[mi];
    sX[t][4] = F[NN + mi];
    sX[t][5] = F[2 * NN + mi];
  }
  const int o = t & 31;
  const int psub = t >> 5;
  const int r0 = psub * 32;
  float yv[32];
  float wc[32];
#pragma unroll
  for (int c = 0; c < 6; ++c) wc[c] = W0[c * 32 + o];
  float bo = b0[o];
  __syncthreads();
#pragma unroll 4
  for (int q2 = 0; q2 < 32; ++q2) {
    const int pp = r0 + q2;
    const float4 x4 = *(const float4*)&sX[pp][0];
    float y = bo;
    y = fmaf(x4.x, wc[0], y);
    y = fmaf(x4.y, wc[1], y);
    y = fmaf(x4.z, wc[2], y);
    y = fmaf(x4.w, wc[3], y);
    y = fmaf(sX[pp][4], wc[4], y);
    y = fmaf(sX[pp][5], wc[5], y);
    yv[q2] = y;
  }
  if (NL == 1) {
    float sA = 0.f, sQ = 0.f;
#pragma unroll
    for (int q2 = 0; q2 < 32; ++q2) { sA += yv[q2]; sQ = fmaf(yv[q2], yv[q2], sQ); }
    atomicAdd(&ssum[o], sA);
    atomicAdd(&ssq[o], sQ);
    __syncthreads();
    if (t < 32) {
      atomicAdd(&statsOut[b * 64 + t], ssum[t]);
      atomicAdd(&statsOut[b * 64 + 32 + t], ssq[t]);
    }
    return;
  }
  {
    const float m = st0[b * 64 + o] * invM;
    const float v = fmaf(st0[b * 64 + 32 + o], invM, -m * m);
    const float rs = rsqrtf(v + 1e-5f);
    __syncthreads();
#pragma unroll
    for (int q2 = 0; q2 < 32; ++q2)
      sX[r0 + q2][o] = fmaxf((yv[q2] - m) * rs, 0.f);
    __syncthreads();
  }
#pragma unroll
  for (int c = 0; c < 32; ++c) wc[c] = W1[c * 32 + o];
  bo = b1[o];
#pragma unroll 2
  for (int q2 = 0; q2 < 32; ++q2) {
    const int pp = r0 + q2;
    float y = bo;
#pragma unroll
    for (int cg = 0; cg < 8; ++cg) {
      const float4 x4 = *(const float4*)&sX[pp][cg * 4];
      y = fmaf(x4.x, wc[cg * 4 + 0], y);
      y = fmaf(x4.y, wc[cg * 4 + 1], y);
      y = fmaf(x4.z, wc[cg * 4 + 2], y);
      y = fmaf(x4.w, wc[cg * 4 + 3], y);
    }
    yv[q2] = y;
  }
  if (NL == 2) {
    float sA = 0.f, sQ = 0.f;
#pragma unroll
    for (int q2 = 0; q2 < 32; ++q2) { sA += yv[q2]; sQ = fmaf(yv[q2], yv[q2], sQ); }
    atomicAdd(&ssum[o], sA);
    atomicAdd(&ssq[o], sQ);
    __syncthreads();
    if (t < 32) {
      atomicAdd(&statsOut[b * 64 + t], ssum[t]);
      atomicAdd(&statsOut[b * 64 + 32 + t], ssq[t]);
    }
    return;
  }
  {
    const float m = st1[b * 64 + o] * invM;
    const float v = fmaf(st1[b * 64 + 32 + o], invM, -m * m);
    const float rs = rsqrtf(v + 1e-5f);
    __syncthreads();
#pragma unroll
    for (int q2 = 0; q2 < 32; ++q2)
      sX[r0 + q2][o] = fmaxf((yv[q2] - m) * rs, 0.f);
    __syncthreads();
  }
#pragma unroll
  for (int c = 0; c < 32; ++c) wc[c] = W2[c * 32 + o];
  bo = b2[o];
  float sA = 0.f, sQ = 0.f;
  float mx = -__builtin_inff();
#pragma unroll 2
  for (int q2 = 0; q2 < 32; ++q2) {
    const int pp = r0 + q2;
    float y = bo;
#pragma unroll
    for (int cg = 0; cg < 8; ++cg) {
      const float4 x4 = *(const float4*)&sX[pp][cg * 4];
      y = fmaf(x4.x, wc[cg * 4 + 0], y);
      y = fmaf(x4.y, wc[cg * 4 + 1], y);
      y = fmaf(x4.z, wc[cg * 4 + 2], y);
      y = fmaf(x4.w, wc[cg * 4 + 3], y);
    }
    sA += y;
    sQ = fmaf(y, y, sQ);
    mx = fmaxf(mx, y);
    if ((q2 & 15) == 15) {
      ff1max[((size_t)((i0 + pp) >> 4) << 5) + o] = mx;
      mx = -__builtin_inff();
    }
  }
  atomicAdd(&ssum[o], sA);
  atomicAdd(&ssq[o], sQ);
  __syncthreads();
  if (t < 32) {
    atomicAdd(&statsOut[b * 64 + t], ssum[t]);
    atomicAdd(&statsOut[b * 64 + 32 + t], ssq[t]);
  }
}

// ------------------------------------------------------ SA2 chain -----------
template <int NL>
__global__ __launch_bounds__(256) void sa2_chain(
    const float* __restrict__ pc, const float* __restrict__ ff1max,
    const float* __restrict__ st2, const int* __restrict__ idx16,
    const float* __restrict__ W0, const float* __restrict__ b0,
    const float* __restrict__ W1, const float* __restrict__ b1,
    const float* __restrict__ W2, const float* __restrict__ b2,
    const float* __restrict__ st3, const float* __restrict__ st4,
    float* __restrict__ ff2max, float* __restrict__ statsOut) {
  __shared__ float sX[256][36];
  __shared__ float smean[32], srstd[32], ssum[16], ssq[16];
  const int t = threadIdx.x;
  const int i0 = blockIdx.x << 8;
  const int b = i0 >> 14;
  const float invM2 = 1.f / 16384.f;
  if (t < 32) {
    const float invM = 1.f / 32768.f;
    const float s = st2[b * 64 + t];
    const float sq = st2[b * 64 + 32 + t];
    const float m = s * invM;
    const float v = fmaf(sq, invM, -m * m);
    smean[t] = m;
    srstd[t] = rsqrtf(v + 1e-5f);
  }
  if (t < 16) { ssum[t] = 0.f; ssq[t] = 0.f; }
  __syncthreads();
  {
    const int i = i0 + t;
    const int n = (i & 16383) >> 3;
    const int k = i & 7;
    const int mi = idx16[(((size_t)(b << 11) + n) << 4) + k];
    const float* P = pc + (size_t)b * (3 * NN);
    sX[t][0] = P[mi] - P[n];
    sX[t][1] = P[NN + mi] - P[NN + n];
    sX[t][2] = P[2 * NN + mi] - P[2 * NN + n];
    const float4* fr4 = (const float4*)(ff1max + (((size_t)(b << 11) + mi) << 5));
#pragma unroll
    for (int cg = 0; cg < 8; ++cg) {
      const float4 v = fr4[cg];
      sX[t][3 + cg * 4 + 0] = fmaxf((v.x - smean[cg * 4 + 0]) * srstd[cg * 4 + 0], 0.f);
      sX[t][3 + cg * 4 + 1] = fmaxf((v.y - smean[cg * 4 + 1]) * srstd[cg * 4 + 1], 0.f);
      sX[t][3 + cg * 4 + 2] = fmaxf((v.z - smean[cg * 4 + 2]) * srstd[cg * 4 + 2], 0.f);
      sX[t][3 + cg * 4 + 3] = fmaxf((v.w - smean[cg * 4 + 3]) * srstd[cg * 4 + 3], 0.f);
    }
  }
  const int o = t & 15;
  const int psub = t >> 4;
  const int r0 = psub * 16;
  float yv[16];
  float wc[35];
#pragma unroll
  for (int c = 0; c < 35; ++c) wc[c] = W0[c * 16 + o];
  float bo = b0[o];
  __syncthreads();
#pragma unroll 2
  for (int q2 = 0; q2 < 16; ++q2) {
    const int pp = r0 + q2;
    float y = bo;
#pragma unroll
    for (int cg = 0; cg < 8; ++cg) {
      const float4 x4 = *(const float4*)&sX[pp][cg * 4];
      y = fmaf(x4.x, wc[cg * 4 + 0], y);
      y = fmaf(x4.y, wc[cg * 4 + 1], y);
      y = fmaf(x4.z, wc[cg * 4 + 2], y);
      y = fmaf(x4.w, wc[cg * 4 + 3], y);
    }
    y = fmaf(sX[pp][32], wc[32], y);
    y = fmaf(sX[pp][33], wc[33], y);
    y = fmaf(sX[pp][34], wc[34], y);
    yv[q2] = y;
  }
  if (NL == 1) {
    float sA = 0.f, sQ = 0.f;
#pragma unroll
    for (int q2 = 0; q2 < 16; ++q2) { sA += yv[q2]; sQ = fmaf(yv[q2], yv[q2], sQ); }
    atomicAdd(&ssum[o], sA);
    atomicAdd(&ssq[o], sQ);
    __syncthreads();
    if (t < 16) {
      atomicAdd(&statsOut[b * 32 + t], ssum[t]);
      atomicAdd(&statsOut[b * 32 + 16 + t], ssq[t]);
    }
    return;
  }
  {
    const float m = st3[b * 32 + o] * invM2;
    const float v = fmaf(st3[b * 32 + 16 + o], invM2, -m * m);
    const float rs = rsqrtf(v + 1e-5f);
    __syncthreads();
#pragma unroll
    for (int q2 = 0; q2 < 16; ++q2)
      sX[r0 + q2][o] = fmaxf((yv[q2] - m) * rs, 0.f);
    __syncthreads();
  }
#pragma unroll
  for (int c = 0; c < 16; ++c) wc[c] = W1[c * 16 + o];
  bo = b1[o];
#pragma unroll 2
  for (int q2 = 0; q2 < 16; ++q2) {
    const int pp = r0 + q2;
    float y = bo;
#pragma unroll
    for (int cg = 0; cg < 4; ++cg) {
      const float4 x4 = *(const float4*)&sX[pp][cg * 4];
      y = fmaf(x4.x, wc[cg * 4 + 0], y);
      y = fmaf(x4.y, wc[cg * 4 + 1], y);
      y = fmaf(x4.z, wc[cg * 4 + 2], y);
      y = fmaf(x4.w, wc[cg * 4 + 3], y);
    }
    yv[q2] = y;
  }
  if (NL == 2) {
    float sA = 0.f, sQ = 0.f;
#pragma unroll
    for (int q2 = 0; q2 < 16; ++q2) { sA += yv[q2]; sQ = fmaf(yv[q2], yv[q2], sQ); }
    atomicAdd(&ssum[o], sA);
    atomicAdd(&ssq[o], sQ);
    __syncthreads();
    if (t < 16) {
      atomicAdd(&statsOut[b * 32 + t], ssum[t]);
      atomicAdd(&statsOut[b * 32 + 16 + t], ssq[t]);
    }
    return;
  }
  {
    const float m = st4[b * 32 + o] * invM2;
    const float v = fmaf(st4[b * 32 + 16 + o], invM2, -m * m);
    const float rs = rsqrtf(v + 1e-5f);
    __syncthreads();
#pragma unroll
    for (int q2 = 0; q2 < 16; ++q2)
      sX[r0 + q2][o] = fmaxf((yv[q2] - m) * rs, 0.f);
    __syncthreads();
  }
#pragma unroll
  for (int c = 0; c < 16; ++c) wc[c] = W2[c * 16 + o];
  bo = b2[o];
  float sA = 0.f, sQ = 0.f;
  float mx = -__builtin_inff();
#pragma unroll 2
  for (int q2 = 0; q2 < 16; ++q2) {
    const int pp = r0 + q2;
    float y = bo;
#pragma unroll
    for (int cg = 0; cg < 4; ++cg) {
      const float4 x4 = *(const float4*)&sX[pp][cg * 4];
      y = fmaf(x4.x, wc[cg * 4 + 0], y);
      y = fmaf(x4.y, wc[cg * 4 + 1], y);
      y = fmaf(x4.z, wc[cg * 4 + 2], y);
      y = fmaf(x4.w, wc[cg * 4 + 3], y);
    }
    sA += y;
    sQ = fmaf(y, y, sQ);
    mx = fmaxf(mx, y);
    if ((q2 & 7) == 7) {
      ff2max[((size_t)((i0 + pp) >> 3) << 4) + o] = mx;
      mx = -__builtin_inff();
    }
  }
  atomicAdd(&ssum[o], sA);
  atomicAdd(&ssq[o], sQ);
  __syncthreads();
  if (t < 16) {
    atomicAdd(&statsOut[b * 32 + t], ssum[t]);
    atomicAdd(&statsOut[b * 32 + 16 + t], ssq[t]);
  }
}

// --------------------------------------------------- gate GEMM: Y = X'W -----
template <int OC, int QGATE>
__global__ __launch_bounds__(256) void gemm_Y(
    const float* __restrict__ pc, const float* __restrict__ G,
    const float* __restrict__ zrmax, const float* __restrict__ stZR,
    const float* __restrict__ flow, const float* __restrict__ ff2max,
    const float* __restrict__ st5, const float* __restrict__ W,
    float* __restrict__ Y) {
  constexpr int OPT = OC / 32;  // 4 (zr) or 2 (q)
  __shared__ __align__(16) float sX[8][217][4];
  const int t = threadIdx.x;
  constexpr int BPB = 64;  // blocks per batch (2048/32)
  const int xcd = blockIdx.x & 7;
  const int kk = blockIdx.x >> 3;
  const int half = (kk >= BPB) ? 1 : 0;
  const int b = xcd * 2 + half;
  const int m0 = (kk - half * BPB) * 32;
  const float* P = pc + (size_t)b * (3 * NN);
  for (int e = t; e < 8 * 216 * 4; e += 256) {
    const int pg = e / 864;
    const int r = e - pg * 864;
    const int c = r >> 2;
    const int k = r & 3;
    const int m = m0 + pg * 4 + k;
    float v = 0.f;
    if (c < 3) v = P[c * NN + m];
    else if (QGATE && c < 67) {
      const int cc = c - 3;
      const float invM = 1.f / 8192.f;
      const float sr = stZR[b * 256 + 64 + cc];
      const float qr = stZR[b * 256 + 192 + cc];
      const float mr = sr * invM;
      const float vr = fmaf(qr, invM, -mr * mr);
      float rv = (zrmax[((size_t)(b << 11) + m) * 128 + 64 + cc] - mr) *
                 rsqrtf(vr + 1e-5f);
      rv = 1.f / (1.f + expf(-rv));
      v = rv * G[((size_t)(b << 11) + m) * 192 + cc];
    } else if (c < 195)
      v = G[((size_t)(b << 11) + m) * 192 + (c - 3)];
    else if (c < 211) {
      const int cc = c - 195;
      const float invM = 1.f / 16384.f;
      const float s = st5[b * 32 + cc];
      const float sq = st5[b * 32 + 16 + cc];
      const float mm = s * invM;
      const float vv = fmaf(sq, invM, -mm * mm);
      v = fmaxf((ff2max[(((size_t)(b << 11) + m) << 4) + cc] - mm) *
                    rsqrtf(vv + 1e-5f),
                0.f);
    } else if (c < 214)
      v = flow[((size_t)(b * 3 + (c - 211))) * NN + m];
    sX[pg][c][k] = v;
  }
  __syncthreads();
  const int oslot = t & 31;
  const int o0 = oslot * OPT;
  const int pg = t >> 5;
  float acc[4][OPT];
#pragma unroll
  for (int k = 0; k < 4; ++k)
#pragma unroll
    for (int j = 0; j < OPT; ++j) acc[k][j] = 0.f;
  const float* Wb = W + o0;
  float w[4][OPT], nw[4][OPT];
#pragma unroll
  for (int cc = 0; cc < 4; ++cc) {
    if (OPT == 4) {
      const float4 w4 = *(const float4*)&Wb[(size_t)cc * OC];
      w[cc][0] = w4.x; w[cc][1] = w4.y; w[cc][2] = w4.z; w[cc][3] = w4.w;
    } else {
      const float2 w2 = *(const float2*)&Wb[(size_t)cc * OC];
      w[cc][0] = w2.x; w[cc][1] = w2.y;
    }
  }
  for (int c0 = 0; c0 < 216; c0 += 4) {
    const int cn = c0 + 4;  // rows to 219 exist (zero-padded)
#pragma unroll
    for (int cc = 0; cc < 4; ++cc) {
      if (OPT == 4) {
        const float4 w4 = *(const float4*)&Wb[(size_t)(cn + cc) * OC];
        nw[cc][0] = w4.x; nw[cc][1] = w4.y; nw[cc][2] = w4.z; nw[cc][3] = w4.w;
      } else {
        const float2 w2 = *(const float2*)&Wb[(size_t)(cn + cc) * OC];
        nw[cc][0] = w2.x; nw[cc][1] = w2.y;
      }
    }
#pragma unroll
    for (int cc = 0; cc < 4; ++cc) {
      const float4 xv = *(const float4*)&sX[pg][c0 + cc][0];
      const float x[4] = {xv.x, xv.y, xv.z, xv.w};
#pragma unroll
      for (int k = 0; k < 4; ++k)
#pragma unroll
        for (int j = 0; j < OPT; ++j)
          acc[k][j] = fmaf(x[k], w[cc][j], acc[k][j]);
    }
#pragma unroll
    for (int cc = 0; cc < 4; ++cc)
#pragma unroll
      for (int j = 0; j < OPT; ++j) w[cc][j] = nw[cc][j];
  }
#pragma unroll
  for (int k = 0; k < 4; ++k) {
    float* dst = &Y[((size_t)(b << 11) + m0 + pg * 4 + k) * OC + o0];
    if (OPT == 4)
      *(float4*)dst = make_float4(acc[k][0], acc[k][1], acc[k][2], acc[k][3]);
    else
      *(float2*)dst = make_float2(acc[k][0], acc[k][1]);
  }
}

// ------------------------------------------- gate reduce: max_k / stats -----
template <int OC>
__global__ __launch_bounds__(256) void gate_reduce(
    const float* __restrict__ pc, const float* __restrict__ Y,
    const int* __restrict__ idx16, const float* __restrict__ W,
    const float* __restrict__ biasA, const float* __restrict__ biasB,
    float* __restrict__ outMax, float* __restrict__ statsOut) {
  constexpr int QO = OC / 32;  // 4 or 2
  __shared__ float ssum[OC], ssq[OC];
  const int t = threadIdx.x;
  const int b = blockIdx.x >> 6;
  const int n0 = (blockIdx.x & 63) << 5;
  const float* P = pc + (size_t)b * (3 * NN);
  if (t < OC) { ssum[t] = 0.f; ssq[t] = 0.f; }
  __syncthreads();
  const int oq = t & 31;
  const int o0 = oq * QO;
  const int ns = t >> 5;
  float w0[QO], w1[QO], w2[QO], bb[QO];
#pragma unroll
  for (int j = 0; j < QO; ++j) {
    w0[j] = W[o0 + j];
    w1[j] = W[OC + o0 + j];
    w2[j] = W[2 * OC + o0 + j];
    const int o = o0 + j;
    bb[j] = (OC == 128) ? ((o < 64) ? biasA[o] : biasB[o - 64]) : biasA[o];
  }
  float s[QO], sq[QO];
#pragma unroll
  for (int j = 0; j < QO; ++j) { s[j] = 0.f; sq[j] = 0.f; }
  for (int it = 0; it < 4; ++it) {
    const int n = n0 + it * 8 + ns;
    const float px = P[n], py = P[NN + n], pz = P[2 * NN + n];
    float qv[QO];
#pragma unroll
    for (int j = 0; j < QO; ++j)
      qv[j] = fmaf(pz, w2[j], fmaf(py, w1[j], px * w0[j]));
    const int4 mi4 =
        *(const int4*)&idx16[((size_t)(b << 11) + n) << 4];
    const int mis[4] = {mi4.x, mi4.y, mi4.z, mi4.w};
    float mx[QO];
#pragma unroll
    for (int j = 0; j < QO; ++j) mx[j] = -__builtin_inff();
#pragma unroll
    for (int k = 0; k < 4; ++k) {
      const float* yr = &Y[((size_t)(b << 11) + mis[k]) * OC + o0];
      float yv[QO];
      if (QO == 4) {
        const float4 y4 = *(const float4*)yr;
        yv[0] = y4.x; yv[1] = y4.y; yv[2] = y4.z; yv[3] = y4.w;
      } else {
        const float2 y2 = *(const float2*)yr;
        yv[0] = y2.x; yv[1] = y2.y;
      }
#pragma unroll
      for (int j = 0; j < QO; ++j) {
        const float y = yv[j] - qv[j] + bb[j];
        s[j] += y;
        sq[j] = fmaf(y, y, sq[j]);
        mx[j] = fmaxf(mx[j], y);
      }
    }
    float* dst = &outMax[((size_t)(b << 11) + n) * OC + o0];
    if (QO == 4)
      *(float4*)dst = make_float4(mx[0], mx[1], mx[2], mx[3]);
    else
      *(float2*)dst = make_float2(mx[0], mx[1]);
  }
#pragma unroll
  for (int j = 0; j < QO; ++j) {
    atomicAdd(&ssum[o0 + j], s[j]);
    atomicAdd(&ssq[o0 + j], sq[j]);
  }
  __syncthreads();
  if (t < OC) {
    atomicAdd(&statsOut[b * (2 * OC) + t], ssum[t]);
    atomicAdd(&statsOut[b * (2 * OC) + OC + t], ssq[t]);
  }
}

// ------------------------------------------------------------ output --------
__global__ __launch_bounds__(256) void final_out(const float* __restrict__ qmax,
                                                 const float* __restrict__ statsQ,
                                                 const float* __restrict__ zrmax,
                                                 const float* __restrict__ stZR,
                                                 const float* __restrict__ h,
                                                 float* __restrict__ out) {
  const int i = blockIdx.x * 256 + threadIdx.x;  // (b, c<64, n)
  const int n = i & 2047;
  const int c = (i >> 11) & 63;
  const int b = i >> 17;
  const int pi = (b << 11) + n;
  const float invM = 1.f / 8192.f;
  const float s = statsQ[b * 128 + c], sq = statsQ[b * 128 + 64 + c];
  const float m = s * invM, v = fmaf(sq, invM, -m * m);
  const float qv = tanhf((qmax[(size_t)pi * 64 + c] - m) * rsqrtf(v + 1e-5f));
  const float sz = stZR[b * 256 + c], qz = stZR[b * 256 + 128 + c];
  const float mz = sz * invM, vz = fmaf(qz, invM, -mz * mz);
  float z = (zrmax[(size_t)pi * 128 + c] - mz) * rsqrtf(vz + 1e-5f);
  z = 1.f / (1.f + expf(-z));
  const float hv = h[i];
  out[i] = (1.f - z) * hv + z * qv;
}

// =============================================================================
extern "C" void kernel_launch(void* const* d_in, const int* in_sizes, int n_in,
                              void* d_out, int out_size, void* d_ws, size_t ws_size,
                              hipStream_t stream) {
  const float* pc = (const float*)d_in[0];
  const float* h = (const float*)d_in[1];
  const float* f1 = (const float*)d_in[2];
  const float* cost = (const float*)d_in[3];
  const float* flow = (const float*)d_in[4];
  const float* w10 = (const float*)d_in[5];
  const float* b10 = (const float*)d_in[6];
  const float* w11 = (const float*)d_in[7];
  const float* b11 = (const float*)d_in[8];
  const float* w12 = (const float*)d_in[9];
  const float* b12 = (const float*)d_in[10];
  const float* w20 = (const float*)d_in[11];
  const float* b20 = (const float*)d_in[12];
  const float* w21 = (const float*)d_in[13];
  const float* b21 = (const float*)d_in[14];
  const float* w22 = (const float*)d_in[15];
  const float* b22 = (const float*)d_in[16];
  const float* gzw = (const float*)d_in[17];
  const float* gzb = (const float*)d_in[18];
  const float* grw = (const float*)d_in[19];
  const float* grb = (const float*)d_in[20];
  const float* gqw = (const float*)d_in[21];
  const float* gqb = (const float*)d_in[22];

  // workspace layout (~77 MB, all f32). KNN scratch (dbuf/ibuf) overlaps the
  // dead ff1max/ff2max/zrmax/Yzr/qmax window (2..50MB) during knn+merge.
  char* ws = (char*)d_ws;
  const size_t MB = 1024 * 1024;
  int* idx16 = (int*)(ws);                 // 2 MB
  float* ff1max = (float*)(ws + 2 * MB);   // 4 MB  (b,n,32)
  float* ff2max = (float*)(ws + 6 * MB);   // 2 MB  (b,n,16)
  float* zrmax = (float*)(ws + 10 * MB);   // 16 MB (b,n,128) — live to final_out
  float* Yzr = (float*)(ws + 26 * MB);     // 16 MB (b,n,128)
  float* Yq = (float*)(ws + 26 * MB);      // 8 MB  — reuses Yzr (dead)
  float* qmax = (float*)(ws + 42 * MB);    // 8 MB
  double* dbuf = (double*)(ws + 4 * MB);   // 33.6 MB (knn scratch, dead window)
  u16* ibuf = (u16*)(ws + 38 * MB);        // 8.4 MB  (knn scratch)
  float* Wzr = (float*)(ws + 50 * MB);     // 112.6 KB (220x128)
  float* Wq = (float*)(ws + 50 * MB + 512 * 1024);  // 56.3 KB (220x64)
  float* stats = (float*)(ws + 51 * MB);   // 43 KB
  float* G = (float*)(ws + 52 * MB);       // 25.2 MB (b,n,192)
  float* st0 = stats;
  float* st1 = stats + 1024;
  float* st2 = stats + 2048;
  float* st3 = stats + 3072;
  float* st4 = stats + 3584;
  float* st5 = stats + 4096;
  float* stZR = stats + 4608;
  float* stQ = stats + 8704;

  hipMemsetAsync(stats, 0, 10752 * sizeof(float), stream);
  pack_all<<<421, 256, 0, stream>>>(h, f1, cost, gzw, grw, gqw, G, Wzr, Wq);
  knn_kernel<<<1024, 256, 0, stream>>>(pc, dbuf, ibuf);
  knn_merge<<<128, 256, 0, stream>>>(dbuf, ibuf, idx16);

  sa1_chain<1><<<2048, 256, 0, stream>>>(pc, flow, idx16, w10, b10, w11, b11,
                                         w12, b12, nullptr, nullptr, nullptr, st0);
  sa1_chain<2><<<2048, 256, 0, stream>>>(pc, flow, idx16, w10, b10, w11, b11,
                                         w12, b12, st0, nullptr, nullptr, st1);
  sa1_chain<3><<<2048, 256, 0, stream>>>(pc, flow, idx16, w10, b10, w11, b11,
                                         w12, b12, st0, st1, ff1max, st2);

  sa2_chain<1><<<1024, 256, 0, stream>>>(pc, ff1max, st2, idx16, w20, b20, w21,
                                         b21, w22, b22, nullptr, nullptr,
                                         nullptr, st3);
  sa2_chain<2><<<1024, 256, 0, stream>>>(pc, ff1max, st2, idx16, w20, b20, w21,
                                         b21, w22, b22, st3, nullptr, nullptr, st4);
  sa2_chain<3><<<1024, 256, 0, stream>>>(pc, ff1max, st2, idx16, w20, b20, w21,
                                         b21, w22, b22, st3, st4, ff2max, st5);

  gemm_Y<128, 0><<<1024, 256, 0, stream>>>(pc, G, nullptr, nullptr, flow,
                                           ff2max, st5, Wzr, Yzr);
  gate_reduce<128><<<1024, 256, 0, stream>>>(pc, Yzr, idx16, Wzr, gzb, grb,
                                             zrmax, stZR);
  gemm_Y<64, 1><<<1024, 256, 0, stream>>>(pc, G, zrmax, stZR, flow, ff2max,
                                          st5, Wq, Yq);
  gate_reduce<64><<<1024, 256, 0, stream>>>(pc, Yq, idx16, Wq, gqb, gqb, qmax,
                                            stQ);
  final_out<<<8192, 256, 0, stream>>>(qmax, stQ, zrmax, stZR, h, (float*)d_out);
}

// Round 15
// 444.674 us; speedup vs baseline: 1.1172x; 1.1172x over previous
//
#include <hip/hip_runtime.h>
#include <hip/hip_bf16.h>
#include <stdint.h>
#include <stddef.h>

#define NN 2048
#define NB 16

typedef unsigned int u32;
typedef unsigned short u16;

// ---------------------------------------------------------------- KNN -------
// R11/R13 version (measured 110us): partitioned scan (64 queries/block, 4
// threads/query, 512 pts each) with conservative f32 screen (running thr);
// exact f64 distance + stable sorted top-16 insert for screened candidates;
// exact 4-way merge (ties -> lower partition = lower index). Selected sets
// identical to the monolithic f64 scan (R4-verified). sp padded to 517.
__global__ __launch_bounds__(256) void knn_kernel(const float* __restrict__ pc,
                                                  int* __restrict__ idx16) {
  __shared__ float4 sp[4 * 517];
  __shared__ double smd[64][4][17];
  __shared__ u16 smi[64][4][16];
  const int t = threadIdx.x;
  const int b = blockIdx.x >> 5;
  const int qbase = (blockIdx.x & 31) << 6;
  const float* __restrict__ P = pc + (size_t)b * (3 * NN);
  for (int i = t; i < NN; i += 256) {
    sp[(i >> 9) * 517 + (i & 511)] =
        make_float4(P[i], P[NN + i], P[2 * NN + i], 0.f);
  }
  __syncthreads();
  const int qloc = t >> 2;
  const int part = t & 3;
  const int n = qbase + qloc;
  const float4 q = sp[(n >> 9) * 517 + (n & 511)];
  const double qx = (double)q.x, qy = (double)q.y, qz = (double)q.z;
  double bd[16];
  int bi[16];
#pragma unroll
  for (int j = 0; j < 16; ++j) { bd[j] = __builtin_inf(); bi[j] = 0; }
  float thr = __builtin_inff();
  const float4* __restrict__ base = &sp[part * 517];
  const int m0 = part << 9;
  for (int j0 = 0; j0 < 512; j0 += 32) {
    u32 mask = 0;
#pragma unroll
    for (int jj = 0; jj < 32; ++jj) {
      const float4 s = base[j0 + jj];
      const float dx = q.x - s.x;
      const float dy = q.y - s.y;
      const float dz = q.z - s.z;
      const float d = fmaf(dx, dx, fmaf(dy, dy, dz * dz));
      mask |= (d <= thr) ? (1u << jj) : 0u;
    }
    while (mask) {
      const int jj = __ffs(mask) - 1;
      mask &= mask - 1;
      const float4 s = base[j0 + jj];
      const double dx = qx - (double)s.x;
      const double dy = qy - (double)s.y;
      const double dz = qz - (double)s.z;
      const double d = dx * dx + dy * dy + dz * dz;
      if (d < bd[15]) {
        const int m = m0 + j0 + jj;
        bool cont = true;
#pragma unroll
        for (int j = 15; j >= 1; --j) {
          const bool mv = d < bd[j - 1];
          if (cont) {
            bd[j] = mv ? bd[j - 1] : d;
            bi[j] = mv ? bi[j - 1] : m;
          }
          cont = cont && mv;
        }
        if (cont) { bd[0] = d; bi[0] = m; }
        thr = (float)bd[15] * 1.00002f;
      }
    }
  }
#pragma unroll
  for (int j = 0; j < 16; ++j) {
    smd[qloc][part][j] = bd[j];
    smi[qloc][part][j] = (u16)bi[j];
  }
  smd[qloc][part][16] = __builtin_inf();
  __syncthreads();
  if (part == 0) {
    int h0 = 0, h1 = 0, h2 = 0, h3 = 0;
    double c0 = smd[qloc][0][0], c1 = smd[qloc][1][0];
    double c2 = smd[qloc][2][0], c3 = smd[qloc][3][0];
    int out[16];
#pragma unroll
    for (int j = 0; j < 16; ++j) {
      double bdm = c0;
      int bp = 0;
      if (c1 < bdm) { bdm = c1; bp = 1; }
      if (c2 < bdm) { bdm = c2; bp = 2; }
      if (c3 < bdm) { bdm = c3; bp = 3; }
      if (bp == 0)      { out[j] = smi[qloc][0][h0]; ++h0; c0 = smd[qloc][0][h0]; }
      else if (bp == 1) { out[j] = smi[qloc][1][h1]; ++h1; c1 = smd[qloc][1][h1]; }
      else if (bp == 2) { out[j] = smi[qloc][2][h2]; ++h2; c2 = smd[qloc][2][h2]; }
      else              { out[j] = smi[qloc][3][h3]; ++h3; c3 = smd[qloc][3][h3]; }
    }
    int4* op = (int4*)(idx16 + (((size_t)b * NN + n) << 4));
    op[0] = make_int4(out[0], out[1], out[2], out[3]);
    op[1] = make_int4(out[4], out[5], out[6], out[7]);
    op[2] = make_int4(out[8], out[9], out[10], out[11]);
    op[3] = make_int4(out[12], out[13], out[14], out[15]);
  }
}

// ------------------- pack G = [h|f1|cost] + pack gate weights ---------------
__global__ __launch_bounds__(256) void pack_all(
    const float* __restrict__ h, const float* __restrict__ f1,
    const float* __restrict__ cost, const float* __restrict__ gzw,
    const float* __restrict__ grw, const float* __restrict__ gqw,
    float* __restrict__ G, float* __restrict__ Wzr, float* __restrict__ Wq) {
  __shared__ float tile[64][133];
  const int t = threadIdx.x;
  if (blockIdx.x >= 256) {
    const int i = (blockIdx.x - 256) * 256 + t;
    if (i < 220 * 128) {
      const int row = i >> 7, col = i & 127;
      float v = 0.f;
      if (row < 214)
        v = (col < 64) ? gzw[row * 64 + col] : grw[row * 64 + (col - 64)];
      Wzr[i] = v;
    } else if (i < 220 * 128 + 220 * 64) {
      const int iq = i - 220 * 128;
      const int row = iq >> 6;
      Wq[iq] = (row < 214) ? gqw[iq] : 0.f;
    }
    return;
  }
  const int b = blockIdx.x >> 4;
  const int n0 = (blockIdx.x & 15) << 7;
  const float* srcs[3] = {h, f1, cost};
#pragma unroll
  for (int a = 0; a < 3; ++a) {
    const float* __restrict__ S = srcs[a] + (size_t)b * 64 * NN;
    __syncthreads();
#pragma unroll
    for (int rep = 0; rep < 32; ++rep) {
      const int idx = rep * 256 + t;
      const int c = idx >> 7, n = idx & 127;
      tile[c][n] = S[c * NN + n0 + n];
    }
    __syncthreads();
#pragma unroll
    for (int rep = 0; rep < 32; ++rep) {
      const int idx = rep * 256 + t;
      const int n = idx >> 6, c = idx & 63;
      G[((size_t)((b << 11) + n0 + n)) * 192 + a * 64 + c] = tile[c][n];
    }
  }
}

// ------------------------------------------------------ SA1 chain -----------
template <int NL>
__global__ __launch_bounds__(256) void sa1_chain(
    const float* __restrict__ pc, const float* __restrict__ flow,
    const int* __restrict__ idx16,
    const float* __restrict__ W0, const float* __restrict__ b0,
    const float* __restrict__ W1, const float* __restrict__ b1,
    const float* __restrict__ W2, const float* __restrict__ b2,
    const float* __restrict__ st0, const float* __restrict__ st1,
    float* __restrict__ ff1max, float* __restrict__ statsOut) {
  __shared__ float sX[256][36];
  __shared__ float ssum[32], ssq[32];
  const int t = threadIdx.x;
  const int i0 = blockIdx.x << 8;
  const int b = i0 >> 15;
  const float invM = 1.f / 32768.f;
  if (t < 32) { ssum[t] = 0.f; ssq[t] = 0.f; }
  {
    const int i = i0 + t;
    const int n = (i & 32767) >> 4;
    const int mi = idx16[i];
    const float* P = pc + (size_t)b * (3 * NN);
    const float* F = flow + (size_t)b * (3 * NN);
    sX[t][0] = P[mi] - P[n];
    sX[t][1] = P[NN + mi] - P[NN + n];
    sX[t][2] = P[2 * NN + mi] - P[2 * NN + n];
    sX[t][3] = F[mi];
    sX[t][4] = F[NN + mi];
    sX[t][5] = F[2 * NN + mi];
  }
  const int o = t & 31;
  const int psub = t >> 5;
  const int r0 = psub * 32;
  float yv[32];
  float wc[32];
#pragma unroll
  for (int c = 0; c < 6; ++c) wc[c] = W0[c * 32 + o];
  float bo = b0[o];
  __syncthreads();
#pragma unroll 4
  for (int q2 = 0; q2 < 32; ++q2) {
    const int pp = r0 + q2;
    const float4 x4 = *(const float4*)&sX[pp][0];
    float y = bo;
    y = fmaf(x4.x, wc[0], y);
    y = fmaf(x4.y, wc[1], y);
    y = fmaf(x4.z, wc[2], y);
    y = fmaf(x4.w, wc[3], y);
    y = fmaf(sX[pp][4], wc[4], y);
    y = fmaf(sX[pp][5], wc[5], y);
    yv[q2] = y;
  }
  if (NL == 1) {
    float sA = 0.f, sQ = 0.f;
#pragma unroll
    for (int q2 = 0; q2 < 32; ++q2) { sA += yv[q2]; sQ = fmaf(yv[q2], yv[q2], sQ); }
    atomicAdd(&ssum[o], sA);
    atomicAdd(&ssq[o], sQ);
    __syncthreads();
    if (t < 32) {
      atomicAdd(&statsOut[b * 64 + t], ssum[t]);
      atomicAdd(&statsOut[b * 64 + 32 + t], ssq[t]);
    }
    return;
  }
  {
    const float m = st0[b * 64 + o] * invM;
    const float v = fmaf(st0[b * 64 + 32 + o], invM, -m * m);
    const float rs = rsqrtf(v + 1e-5f);
    __syncthreads();
#pragma unroll
    for (int q2 = 0; q2 < 32; ++q2)
      sX[r0 + q2][o] = fmaxf((yv[q2] - m) * rs, 0.f);
    __syncthreads();
  }
#pragma unroll
  for (int c = 0; c < 32; ++c) wc[c] = W1[c * 32 + o];
  bo = b1[o];
#pragma unroll 2
  for (int q2 = 0; q2 < 32; ++q2) {
    const int pp = r0 + q2;
    float y = bo;
#pragma unroll
    for (int cg = 0; cg < 8; ++cg) {
      const float4 x4 = *(const float4*)&sX[pp][cg * 4];
      y = fmaf(x4.x, wc[cg * 4 + 0], y);
      y = fmaf(x4.y, wc[cg * 4 + 1], y);
      y = fmaf(x4.z, wc[cg * 4 + 2], y);
      y = fmaf(x4.w, wc[cg * 4 + 3], y);
    }
    yv[q2] = y;
  }
  if (NL == 2) {
    float sA = 0.f, sQ = 0.f;
#pragma unroll
    for (int q2 = 0; q2 < 32; ++q2) { sA += yv[q2]; sQ = fmaf(yv[q2], yv[q2], sQ); }
    atomicAdd(&ssum[o], sA);
    atomicAdd(&ssq[o], sQ);
    __syncthreads();
    if (t < 32) {
      atomicAdd(&statsOut[b * 64 + t], ssum[t]);
      atomicAdd(&statsOut[b * 64 + 32 + t], ssq[t]);
    }
    return;
  }
  {
    const float m = st1[b * 64 + o] * invM;
    const float v = fmaf(st1[b * 64 + 32 + o], invM, -m * m);
    const float rs = rsqrtf(v + 1e-5f);
    __syncthreads();
#pragma unroll
    for (int q2 = 0; q2 < 32; ++q2)
      sX[r0 + q2][o] = fmaxf((yv[q2] - m) * rs, 0.f);
    __syncthreads();
  }
#pragma unroll
  for (int c = 0; c < 32; ++c) wc[c] = W2[c * 32 + o];
  bo = b2[o];
  float sA = 0.f, sQ = 0.f;
  float mx = -__builtin_inff();
#pragma unroll 2
  for (int q2 = 0; q2 < 32; ++q2) {
    const int pp = r0 + q2;
    float y = bo;
#pragma unroll
    for (int cg = 0; cg < 8; ++cg) {
      const float4 x4 = *(const float4*)&sX[pp][cg * 4];
      y = fmaf(x4.x, wc[cg * 4 + 0], y);
      y = fmaf(x4.y, wc[cg * 4 + 1], y);
      y = fmaf(x4.z, wc[cg * 4 + 2], y);
      y = fmaf(x4.w, wc[cg * 4 + 3], y);
    }
    sA += y;
    sQ = fmaf(y, y, sQ);
    mx = fmaxf(mx, y);
    if ((q2 & 15) == 15) {
      ff1max[((size_t)((i0 + pp) >> 4) << 5) + o] = mx;
      mx = -__builtin_inff();
    }
  }
  atomicAdd(&ssum[o], sA);
  atomicAdd(&ssq[o], sQ);
  __syncthreads();
  if (t < 32) {
    atomicAdd(&statsOut[b * 64 + t], ssum[t]);
    atomicAdd(&statsOut[b * 64 + 32 + t], ssq[t]);
  }
}

// ------------------------------------------------------ SA2 chain -----------
template <int NL>
__global__ __launch_bounds__(256) void sa2_chain(
    const float* __restrict__ pc, const float* __restrict__ ff1max,
    const float* __restrict__ st2, const int* __restrict__ idx16,
    const float* __restrict__ W0, const float* __restrict__ b0,
    const float* __restrict__ W1, const float* __restrict__ b1,
    const float* __restrict__ W2, const float* __restrict__ b2,
    const float* __restrict__ st3, const float* __restrict__ st4,
    float* __restrict__ ff2max, float* __restrict__ statsOut) {
  __shared__ float sX[256][36];
  __shared__ float smean[32], srstd[32], ssum[16], ssq[16];
  const int t = threadIdx.x;
  const int i0 = blockIdx.x << 8;
  const int b = i0 >> 14;
  const float invM2 = 1.f / 16384.f;
  if (t < 32) {
    const float invM = 1.f / 32768.f;
    const float s = st2[b * 64 + t];
    const float sq = st2[b * 64 + 32 + t];
    const float m = s * invM;
    const float v = fmaf(sq, invM, -m * m);
    smean[t] = m;
    srstd[t] = rsqrtf(v + 1e-5f);
  }
  if (t < 16) { ssum[t] = 0.f; ssq[t] = 0.f; }
  __syncthreads();
  {
    const int i = i0 + t;
    const int n = (i & 16383) >> 3;
    const int k = i & 7;
    const int mi = idx16[(((size_t)(b << 11) + n) << 4) + k];
    const float* P = pc + (size_t)b * (3 * NN);
    sX[t][0] = P[mi] - P[n];
    sX[t][1] = P[NN + mi] - P[NN + n];
    sX[t][2] = P[2 * NN + mi] - P[2 * NN + n];
    const float4* fr4 = (const float4*)(ff1max + (((size_t)(b << 11) + mi) << 5));
#pragma unroll
    for (int cg = 0; cg < 8; ++cg) {
      const float4 v = fr4[cg];
      sX[t][3 + cg * 4 + 0] = fmaxf((v.x - smean[cg * 4 + 0]) * srstd[cg * 4 + 0], 0.f);
      sX[t][3 + cg * 4 + 1] = fmaxf((v.y - smean[cg * 4 + 1]) * srstd[cg * 4 + 1], 0.f);
      sX[t][3 + cg * 4 + 2] = fmaxf((v.z - smean[cg * 4 + 2]) * srstd[cg * 4 + 2], 0.f);
      sX[t][3 + cg * 4 + 3] = fmaxf((v.w - smean[cg * 4 + 3]) * srstd[cg * 4 + 3], 0.f);
    }
  }
  const int o = t & 15;
  const int psub = t >> 4;
  const int r0 = psub * 16;
  float yv[16];
  float wc[35];
#pragma unroll
  for (int c = 0; c < 35; ++c) wc[c] = W0[c * 16 + o];
  float bo = b0[o];
  __syncthreads();
#pragma unroll 2
  for (int q2 = 0; q2 < 16; ++q2) {
    const int pp = r0 + q2;
    float y = bo;
#pragma unroll
    for (int cg = 0; cg < 8; ++cg) {
      const float4 x4 = *(const float4*)&sX[pp][cg * 4];
      y = fmaf(x4.x, wc[cg * 4 + 0], y);
      y = fmaf(x4.y, wc[cg * 4 + 1], y);
      y = fmaf(x4.z, wc[cg * 4 + 2], y);
      y = fmaf(x4.w, wc[cg * 4 + 3], y);
    }
    y = fmaf(sX[pp][32], wc[32], y);
    y = fmaf(sX[pp][33], wc[33], y);
    y = fmaf(sX[pp][34], wc[34], y);
    yv[q2] = y;
  }
  if (NL == 1) {
    float sA = 0.f, sQ = 0.f;
#pragma unroll
    for (int q2 = 0; q2 < 16; ++q2) { sA += yv[q2]; sQ = fmaf(yv[q2], yv[q2], sQ); }
    atomicAdd(&ssum[o], sA);
    atomicAdd(&ssq[o], sQ);
    __syncthreads();
    if (t < 16) {
      atomicAdd(&statsOut[b * 32 + t], ssum[t]);
      atomicAdd(&statsOut[b * 32 + 16 + t], ssq[t]);
    }
    return;
  }
  {
    const float m = st3[b * 32 + o] * invM2;
    const float v = fmaf(st3[b * 32 + 16 + o], invM2, -m * m);
    const float rs = rsqrtf(v + 1e-5f);
    __syncthreads();
#pragma unroll
    for (int q2 = 0; q2 < 16; ++q2)
      sX[r0 + q2][o] = fmaxf((yv[q2] - m) * rs, 0.f);
    __syncthreads();
  }
#pragma unroll
  for (int c = 0; c < 16; ++c) wc[c] = W1[c * 16 + o];
  bo = b1[o];
#pragma unroll 2
  for (int q2 = 0; q2 < 16; ++q2) {
    const int pp = r0 + q2;
    float y = bo;
#pragma unroll
    for (int cg = 0; cg < 4; ++cg) {
      const float4 x4 = *(const float4*)&sX[pp][cg * 4];
      y = fmaf(x4.x, wc[cg * 4 + 0], y);
      y = fmaf(x4.y, wc[cg * 4 + 1], y);
      y = fmaf(x4.z, wc[cg * 4 + 2], y);
      y = fmaf(x4.w, wc[cg * 4 + 3], y);
    }
    yv[q2] = y;
  }
  if (NL == 2) {
    float sA = 0.f, sQ = 0.f;
#pragma unroll
    for (int q2 = 0; q2 < 16; ++q2) { sA += yv[q2]; sQ = fmaf(yv[q2], yv[q2], sQ); }
    atomicAdd(&ssum[o], sA);
    atomicAdd(&ssq[o], sQ);
    __syncthreads();
    if (t < 16) {
      atomicAdd(&statsOut[b * 32 + t], ssum[t]);
      atomicAdd(&statsOut[b * 32 + 16 + t], ssq[t]);
    }
    return;
  }
  {
    const float m = st4[b * 32 + o] * invM2;
    const float v = fmaf(st4[b * 32 + 16 + o], invM2, -m * m);
    const float rs = rsqrtf(v + 1e-5f);
    __syncthreads();
#pragma unroll
    for (int q2 = 0; q2 < 16; ++q2)
      sX[r0 + q2][o] = fmaxf((yv[q2] - m) * rs, 0.f);
    __syncthreads();
  }
#pragma unroll
  for (int c = 0; c < 16; ++c) wc[c] = W2[c * 16 + o];
  bo = b2[o];
  float sA = 0.f, sQ = 0.f;
  float mx = -__builtin_inff();
#pragma unroll 2
  for (int q2 = 0; q2 < 16; ++q2) {
    const int pp = r0 + q2;
    float y = bo;
#pragma unroll
    for (int cg = 0; cg < 4; ++cg) {
      const float4 x4 = *(const float4*)&sX[pp][cg * 4];
      y = fmaf(x4.x, wc[cg * 4 + 0], y);
      y = fmaf(x4.y, wc[cg * 4 + 1], y);
      y = fmaf(x4.z, wc[cg * 4 + 2], y);
      y = fmaf(x4.w, wc[cg * 4 + 3], y);
    }
    sA += y;
    sQ = fmaf(y, y, sQ);
    mx = fmaxf(mx, y);
    if ((q2 & 7) == 7) {
      ff2max[((size_t)((i0 + pp) >> 3) << 4) + o] = mx;
      mx = -__builtin_inff();
    }
  }
  atomicAdd(&ssum[o], sA);
  atomicAdd(&ssq[o], sQ);
  __syncthreads();
  if (t < 16) {
    atomicAdd(&statsOut[b * 32 + t], ssum[t]);
    atomicAdd(&statsOut[b * 32 + 16 + t], ssq[t]);
  }
}

// --------------------------------------------------- gate GEMM: Y = X'W -----
template <int OC, int QGATE>
__global__ __launch_bounds__(256) void gemm_Y(
    const float* __restrict__ pc, const float* __restrict__ G,
    const float* __restrict__ zrmax, const float* __restrict__ stZR,
    const float* __restrict__ flow, const float* __restrict__ ff2max,
    const float* __restrict__ st5, const float* __restrict__ W,
    float* __restrict__ Y) {
  constexpr int OPT = OC / 32;  // 4 (zr) or 2 (q)
  __shared__ __align__(16) float sX[8][217][4];
  const int t = threadIdx.x;
  constexpr int BPB = 64;  // blocks per batch (2048/32)
  const int xcd = blockIdx.x & 7;
  const int kk = blockIdx.x >> 3;
  const int half = (kk >= BPB) ? 1 : 0;
  const int b = xcd * 2 + half;
  const int m0 = (kk - half * BPB) * 32;
  const float* P = pc + (size_t)b * (3 * NN);
  for (int e = t; e < 8 * 216 * 4; e += 256) {
    const int pg = e / 864;
    const int r = e - pg * 864;
    const int c = r >> 2;
    const int k = r & 3;
    const int m = m0 + pg * 4 + k;
    float v = 0.f;
    if (c < 3) v = P[c * NN + m];
    else if (QGATE && c < 67) {
      const int cc = c - 3;
      const float invM = 1.f / 8192.f;
      const float sr = stZR[b * 256 + 64 + cc];
      const float qr = stZR[b * 256 + 192 + cc];
      const float mr = sr * invM;
      const float vr = fmaf(qr, invM, -mr * mr);
      float rv = (zrmax[((size_t)(b << 11) + m) * 128 + 64 + cc] - mr) *
                 rsqrtf(vr + 1e-5f);
      rv = 1.f / (1.f + expf(-rv));
      v = rv * G[((size_t)(b << 11) + m) * 192 + cc];
    } else if (c < 195)
      v = G[((size_t)(b << 11) + m) * 192 + (c - 3)];
    else if (c < 211) {
      const int cc = c - 195;
      const float invM = 1.f / 16384.f;
      const float s = st5[b * 32 + cc];
      const float sq = st5[b * 32 + 16 + cc];
      const float mm = s * invM;
      const float vv = fmaf(sq, invM, -mm * mm);
      v = fmaxf((ff2max[(((size_t)(b << 11) + m) << 4) + cc] - mm) *
                    rsqrtf(vv + 1e-5f),
                0.f);
    } else if (c < 214)
      v = flow[((size_t)(b * 3 + (c - 211))) * NN + m];
    sX[pg][c][k] = v;
  }
  __syncthreads();
  const int oslot = t & 31;
  const int o0 = oslot * OPT;
  const int pg = t >> 5;
  float acc[4][OPT];
#pragma unroll
  for (int k = 0; k < 4; ++k)
#pragma unroll
    for (int j = 0; j < OPT; ++j) acc[k][j] = 0.f;
  const float* Wb = W + o0;
  float w[4][OPT], nw[4][OPT];
#pragma unroll
  for (int cc = 0; cc < 4; ++cc) {
    if (OPT == 4) {
      const float4 w4 = *(const float4*)&Wb[(size_t)cc * OC];
      w[cc][0] = w4.x; w[cc][1] = w4.y; w[cc][2] = w4.z; w[cc][3] = w4.w;
    } else {
      const float2 w2 = *(const float2*)&Wb[(size_t)cc * OC];
      w[cc][0] = w2.x; w[cc][1] = w2.y;
    }
  }
  for (int c0 = 0; c0 < 216; c0 += 4) {
    const int cn = c0 + 4;  // rows to 219 exist (zero-padded)
#pragma unroll
    for (int cc = 0; cc < 4; ++cc) {
      if (OPT == 4) {
        const float4 w4 = *(const float4*)&Wb[(size_t)(cn + cc) * OC];
        nw[cc][0] = w4.x; nw[cc][1] = w4.y; nw[cc][2] = w4.z; nw[cc][3] = w4.w;
      } else {
        const float2 w2 = *(const float2*)&Wb[(size_t)(cn + cc) * OC];
        nw[cc][0] = w2.x; nw[cc][1] = w2.y;
      }
    }
#pragma unroll
    for (int cc = 0; cc < 4; ++cc) {
      const float4 xv = *(const float4*)&sX[pg][c0 + cc][0];
      const float x[4] = {xv.x, xv.y, xv.z, xv.w};
#pragma unroll
      for (int k = 0; k < 4; ++k)
#pragma unroll
        for (int j = 0; j < OPT; ++j)
          acc[k][j] = fmaf(x[k], w[cc][j], acc[k][j]);
    }
#pragma unroll
    for (int cc = 0; cc < 4; ++cc)
#pragma unroll
      for (int j = 0; j < OPT; ++j) w[cc][j] = nw[cc][j];
  }
#pragma unroll
  for (int k = 0; k < 4; ++k) {
    float* dst = &Y[((size_t)(b << 11) + m0 + pg * 4 + k) * OC + o0];
    if (OPT == 4)
      *(float4*)dst = make_float4(acc[k][0], acc[k][1], acc[k][2], acc[k][3]);
    else
      *(float2*)dst = make_float2(acc[k][0], acc[k][1]);
  }
}

// ------------------------------------------- gate reduce: max_k / stats -----
template <int OC>
__global__ __launch_bounds__(256) void gate_reduce(
    const float* __restrict__ pc, const float* __restrict__ Y,
    const int* __restrict__ idx16, const float* __restrict__ W,
    const float* __restrict__ biasA, const float* __restrict__ biasB,
    float* __restrict__ outMax, float* __restrict__ statsOut) {
  constexpr int QO = OC / 32;  // 4 or 2
  __shared__ float ssum[OC], ssq[OC];
  const int t = threadIdx.x;
  const int b = blockIdx.x >> 6;
  const int n0 = (blockIdx.x & 63) << 5;
  const float* P = pc + (size_t)b * (3 * NN);
  if (t < OC) { ssum[t] = 0.f; ssq[t] = 0.f; }
  __syncthreads();
  const int oq = t & 31;
  const int o0 = oq * QO;
  const int ns = t >> 5;
  float w0[QO], w1[QO], w2[QO], bb[QO];
#pragma unroll
  for (int j = 0; j < QO; ++j) {
    w0[j] = W[o0 + j];
    w1[j] = W[OC + o0 + j];
    w2[j] = W[2 * OC + o0 + j];
    const int o = o0 + j;
    bb[j] = (OC == 128) ? ((o < 64) ? biasA[o] : biasB[o - 64]) : biasA[o];
  }
  float s[QO], sq[QO];
#pragma unroll
  for (int j = 0; j < QO; ++j) { s[j] = 0.f; sq[j] = 0.f; }
  for (int it = 0; it < 4; ++it) {
    const int n = n0 + it * 8 + ns;
    const float px = P[n], py = P[NN + n], pz = P[2 * NN + n];
    float qv[QO];
#pragma unroll
    for (int j = 0; j < QO; ++j)
      qv[j] = fmaf(pz, w2[j], fmaf(py, w1[j], px * w0[j]));
    const int4 mi4 =
        *(const int4*)&idx16[((size_t)(b << 11) + n) << 4];
    const int mis[4] = {mi4.x, mi4.y, mi4.z, mi4.w};
    float mx[QO];
#pragma unroll
    for (int j = 0; j < QO; ++j) mx[j] = -__builtin_inff();
#pragma unroll
    for (int k = 0; k < 4; ++k) {
      const float* yr = &Y[((size_t)(b << 11) + mis[k]) * OC + o0];
      float yv[QO];
      if (QO == 4) {
        const float4 y4 = *(const float4*)yr;
        yv[0] = y4.x; yv[1] = y4.y; yv[2] = y4.z; yv[3] = y4.w;
      } else {
        const float2 y2 = *(const float2*)yr;
        yv[0] = y2.x; yv[1] = y2.y;
      }
#pragma unroll
      for (int j = 0; j < QO; ++j) {
        const float y = yv[j] - qv[j] + bb[j];
        s[j] += y;
        sq[j] = fmaf(y, y, sq[j]);
        mx[j] = fmaxf(mx[j], y);
      }
    }
    float* dst = &outMax[((size_t)(b << 11) + n) * OC + o0];
    if (QO == 4)
      *(float4*)dst = make_float4(mx[0], mx[1], mx[2], mx[3]);
    else
      *(float2*)dst = make_float2(mx[0], mx[1]);
  }
#pragma unroll
  for (int j = 0; j < QO; ++j) {
    atomicAdd(&ssum[o0 + j], s[j]);
    atomicAdd(&ssq[o0 + j], sq[j]);
  }
  __syncthreads();
  if (t < OC) {
    atomicAdd(&statsOut[b * (2 * OC) + t], ssum[t]);
    atomicAdd(&statsOut[b * (2 * OC) + OC + t], ssq[t]);
  }
}

// ------------------------------------------------------------ output --------
__global__ __launch_bounds__(256) void final_out(const float* __restrict__ qmax,
                                                 const float* __restrict__ statsQ,
                                                 const float* __restrict__ zrmax,
                                                 const float* __restrict__ stZR,
                                                 const float* __restrict__ h,
                                                 float* __restrict__ out) {
  const int i = blockIdx.x * 256 + threadIdx.x;  // (b, c<64, n)
  const int n = i & 2047;
  const int c = (i >> 11) & 63;
  const int b = i >> 17;
  const int pi = (b << 11) + n;
  const float invM = 1.f / 8192.f;
  const float s = statsQ[b * 128 + c], sq = statsQ[b * 128 + 64 + c];
  const float m = s * invM, v = fmaf(sq, invM, -m * m);
  const float qv = tanhf((qmax[(size_t)pi * 64 + c] - m) * rsqrtf(v + 1e-5f));
  const float sz = stZR[b * 256 + c], qz = stZR[b * 256 + 128 + c];
  const float mz = sz * invM, vz = fmaf(qz, invM, -mz * mz);
  float z = (zrmax[(size_t)pi * 128 + c] - mz) * rsqrtf(vz + 1e-5f);
  z = 1.f / (1.f + expf(-z));
  const float hv = h[i];
  out[i] = (1.f - z) * hv + z * qv;
}

// =============================================================================
extern "C" void kernel_launch(void* const* d_in, const int* in_sizes, int n_in,
                              void* d_out, int out_size, void* d_ws, size_t ws_size,
                              hipStream_t stream) {
  const float* pc = (const float*)d_in[0];
  const float* h = (const float*)d_in[1];
  const float* f1 = (const float*)d_in[2];
  const float* cost = (const float*)d_in[3];
  const float* flow = (const float*)d_in[4];
  const float* w10 = (const float*)d_in[5];
  const float* b10 = (const float*)d_in[6];
  const float* w11 = (const float*)d_in[7];
  const float* b11 = (const float*)d_in[8];
  const float* w12 = (const float*)d_in[9];
  const float* b12 = (const float*)d_in[10];
  const float* w20 = (const float*)d_in[11];
  const float* b20 = (const float*)d_in[12];
  const float* w21 = (const float*)d_in[13];
  const float* b21 = (const float*)d_in[14];
  const float* w22 = (const float*)d_in[15];
  const float* b22 = (const float*)d_in[16];
  const float* gzw = (const float*)d_in[17];
  const float* gzb = (const float*)d_in[18];
  const float* grw = (const float*)d_in[19];
  const float* grb = (const float*)d_in[20];
  const float* gqw = (const float*)d_in[21];
  const float* gqb = (const float*)d_in[22];

  // workspace layout (~77 MB, all f32)
  char* ws = (char*)d_ws;
  const size_t MB = 1024 * 1024;
  int* idx16 = (int*)(ws);                 // 2 MB
  float* ff1max = (float*)(ws + 2 * MB);   // 4 MB  (b,n,32)
  float* ff2max = (float*)(ws + 6 * MB);   // 2 MB  (b,n,16)
  float* zrmax = (float*)(ws + 10 * MB);   // 16 MB (b,n,128) — live to final_out
  float* Yzr = (float*)(ws + 26 * MB);     // 16 MB (b,n,128)
  float* Yq = (float*)(ws + 26 * MB);      // 8 MB  — reuses Yzr (dead)
  float* qmax = (float*)(ws + 42 * MB);    // 8 MB
  float* Wzr = (float*)(ws + 50 * MB);     // 112.6 KB (220x128)
  float* Wq = (float*)(ws + 50 * MB + 512 * 1024);  // 56.3 KB (220x64)
  float* stats = (float*)(ws + 51 * MB);   // 43 KB
  float* G = (float*)(ws + 52 * MB);       // 25.2 MB (b,n,192)
  float* st0 = stats;
  float* st1 = stats + 1024;
  float* st2 = stats + 2048;
  float* st3 = stats + 3072;
  float* st4 = stats + 3584;
  float* st5 = stats + 4096;
  float* stZR = stats + 4608;
  float* stQ = stats + 8704;

  hipMemsetAsync(stats, 0, 10752 * sizeof(float), stream);
  pack_all<<<421, 256, 0, stream>>>(h, f1, cost, gzw, grw, gqw, G, Wzr, Wq);
  knn_kernel<<<512, 256, 0, stream>>>(pc, idx16);

  sa1_chain<1><<<2048, 256, 0, stream>>>(pc, flow, idx16, w10, b10, w11, b11,
                                         w12, b12, nullptr, nullptr, nullptr, st0);
  sa1_chain<2><<<2048, 256, 0, stream>>>(pc, flow, idx16, w10, b10, w11, b11,
                                         w12, b12, st0, nullptr, nullptr, st1);
  sa1_chain<3><<<2048, 256, 0, stream>>>(pc, flow, idx16, w10, b10, w11, b11,
                                         w12, b12, st0, st1, ff1max, st2);

  sa2_chain<1><<<1024, 256, 0, stream>>>(pc, ff1max, st2, idx16, w20, b20, w21,
                                         b21, w22, b22, nullptr, nullptr,
                                         nullptr, st3);
  sa2_chain<2><<<1024, 256, 0, stream>>>(pc, ff1max, st2, idx16, w20, b20, w21,
                                         b21, w22, b22, st3, nullptr, nullptr, st4);
  sa2_chain<3><<<1024, 256, 0, stream>>>(pc, ff1max, st2, idx16, w20, b20, w21,
                                         b21, w22, b22, st3, st4, ff2max, st5);

  gemm_Y<128, 0><<<1024, 256, 0, stream>>>(pc, G, nullptr, nullptr, flow,
                                           ff2max, st5, Wzr, Yzr);
  gate_reduce<128><<<1024, 256, 0, stream>>>(pc, Yzr, idx16, Wzr, gzb, grb,
                                             zrmax, stZR);
  gemm_Y<64, 1><<<1024, 256, 0, stream>>>(pc, G, zrmax, stZR, flow, ff2max,
                                          st5, Wq, Yq);
  gate_reduce<64><<<1024, 256, 0, stream>>>(pc, Yq, idx16, Wq, gqb, gqb, qmax,
                                            stQ);
  final_out<<<8192, 256, 0, stream>>>(qmax, stQ, zrmax, stZR, h, (float*)d_out);
}